// Round 2
// baseline (501.689 us; speedup 1.0000x reference)
//
#include <hip/hip_runtime.h>
#include <hip/hip_bf16.h>
#include <math.h>

#define B_    32
#define N_    4096
#define M_    4096
#define D_    256
#define POOL_ 30
#define LEN_  64
#define TOPK_ 5
#define HIST_ 100
#define L_    320   // TOPK_*LEN_

// output layout (floats)
#define FS_OFF  33554432ull          // final_scores [32][30]
#define SEL_OFF (FS_OFF + 960ull)    // sel_idx [32][5] (as float values)
#define DIV_OFF (SEL_OFF + 160ull)   // diversity [30]

// ws layout (byte offsets)
#define WS_PART   0ull        // [32][32][256] f32 partial sums (1 MiB)
#define WS_XMEAN  1048576ull  // [32][256] f32
#define WS_XNORM  1081344ull  // [32] f32
#define WS_LOGITS 1081472ull  // [32][30] f32
#define WS_SEL    1085312ull  // [5] int
#define WS_BPN    1085440ull  // [320][256] bf16 (normalized keys)
#define WS_BPT    1249280ull  // [256][320] bf16 (raw V, transposed)

typedef short bf16x8 __attribute__((ext_vector_type(8)));   // 8 bf16 (4 VGPRs)
typedef float f32x4  __attribute__((ext_vector_type(4)));

// ---------------- x_mean partial sums ----------------
__global__ void k_partial(const float* __restrict__ x, float* __restrict__ part) {
    int c = blockIdx.x, b = blockIdx.y, d = threadIdx.x;
    const float* p = x + ((size_t)b * N_ + (size_t)c * 128) * D_ + d;
    float s = 0.f;
    #pragma unroll 8
    for (int n = 0; n < 128; ++n) s += p[(size_t)n * D_];
    part[(b * 32 + c) * D_ + d] = s;
}

// ---------------- finalize x_mean + its L2 norm ----------------
__global__ void k_xmean(const float* __restrict__ part, float* __restrict__ xm,
                        float* __restrict__ xnorm) {
    int b = blockIdx.x, d = threadIdx.x;
    float s = 0.f;
    for (int c = 0; c < 32; ++c) s += part[(b * 32 + c) * D_ + d];
    s *= (1.0f / N_);
    xm[b * D_ + d] = s;
    __shared__ float red[256];
    red[d] = s * s;
    __syncthreads();
    for (int off = 128; off > 0; off >>= 1) {
        if (d < off) red[d] += red[d + off];
        __syncthreads();
    }
    if (d == 0) xnorm[b] = sqrtf(red[0]);
}

// ---------------- batched MLP relevance logits ----------------
__global__ void k_mlp(const float* __restrict__ xm, const float* __restrict__ pk,
                      const float* __restrict__ W1, const float* __restrict__ b1,
                      const float* __restrict__ g, const float* __restrict__ be,
                      const float* __restrict__ W2, const float* __restrict__ b2,
                      float* __restrict__ logits) {
    int p = blockIdx.x, b = blockIdx.y, j = threadIdx.x;
    const float* xv = xm + b * D_;
    const float* pv = pk + p * D_;
    float h = b1[j];
    for (int d = 0; d < D_; ++d) h += pv[d] * xv[d] * W1[d * 256 + j];
    __shared__ float red[256];
    red[j] = h;
    __syncthreads();
    for (int off = 128; off > 0; off >>= 1) { if (j < off) red[j] += red[j + off]; __syncthreads(); }
    float mu = red[0] * (1.0f / 256.0f);
    __syncthreads();
    float dd = h - mu;
    red[j] = dd * dd;
    __syncthreads();
    for (int off = 128; off > 0; off >>= 1) { if (j < off) red[j] += red[j + off]; __syncthreads(); }
    float var = red[0] * (1.0f / 256.0f);
    __syncthreads();
    float hn = (dd / sqrtf(var + 1e-5f)) * g[j] + be[j];
    float ge = 0.5f * hn * (1.0f + erff(hn * 0.70710678118654752f)); // exact gelu
    red[j] = ge * W2[j];
    __syncthreads();
    for (int off = 128; off > 0; off >>= 1) { if (j < off) red[j] += red[j + off]; __syncthreads(); }
    if (j == 0) logits[b * POOL_ + p] = red[0] + b2[0];
}

// ---------------- scores, softmax, top-k, small outputs ----------------
__global__ void k_score(const float* __restrict__ xm, const float* __restrict__ xnorm,
                        const float* __restrict__ pk, const float* __restrict__ hist,
                        const float* __restrict__ logits, float* __restrict__ out,
                        int* __restrict__ sel_ws) {
    __shared__ float pkinv[POOL_], xinv[B_], divs[POOL_];
    __shared__ float rel[B_ * POOL_], fin[B_ * POOL_], bs[POOL_];
    __shared__ int sel_s[TOPK_];
    int t = threadIdx.x;

    if (t < POOL_) {
        float s = 0.f;
        for (int d = 0; d < D_; ++d) { float v = pk[t * D_ + d]; s += v * v; }
        pkinv[t] = 1.0f / fmaxf(sqrtf(s), 1e-12f);
        float hs = 0.f;
        for (int h2 = 0; h2 < HIST_; ++h2) hs += hist[h2 * POOL_ + t];
        divs[t] = 1.0f - hs * (1.0f / HIST_);
    }
    if (t >= 32 && t < 64) xinv[t - 32] = 1.0f / fmaxf(xnorm[t - 32], 1e-12f);
    if (t >= 64 && t < 96) {
        int b = t - 64;
        float mx = -1e30f;
        for (int p = 0; p < POOL_; ++p) mx = fmaxf(mx, logits[b * POOL_ + p]);
        float s = 0.f;
        for (int p = 0; p < POOL_; ++p) { float e = expf(logits[b * POOL_ + p] - mx); rel[b * POOL_ + p] = e; s += e; }
        float inv = 1.0f / s;
        for (int p = 0; p < POOL_; ++p) rel[b * POOL_ + p] *= inv;
    }
    __syncthreads();
    for (int pair = t; pair < B_ * POOL_; pair += 256) {
        int b = pair / POOL_, p = pair % POOL_;
        const float* xv = xm + b * D_;
        const float* pv = pk + p * D_;
        float dot = 0.f;
        for (int d = 0; d < D_; ++d) dot += xv[d] * pv[d];
        float sim = dot * xinv[b] * pkinv[p];
        float f = 0.5f * sim + 0.3f * divs[p] + 0.2f * rel[pair];
        fin[pair] = f;
        out[FS_OFF + pair] = f;
    }
    __syncthreads();
    if (t < POOL_) {
        float s = 0.f;
        for (int b = 0; b < B_; ++b) s += fin[b * POOL_ + t];
        bs[t] = s * (1.0f / B_);
    }
    __syncthreads();
    if (t == 0) {
        float v[POOL_];
        for (int p = 0; p < POOL_; ++p) v[p] = bs[p];
        for (int k2 = 0; k2 < TOPK_; ++k2) {
            int am = 0; float mv = v[0];
            for (int p = 1; p < POOL_; ++p) if (v[p] > mv) { mv = v[p]; am = p; }
            sel_s[k2] = am; v[am] = -1e30f;
        }
        for (int k2 = 0; k2 < TOPK_; ++k2) sel_ws[k2] = sel_s[k2];
    }
    __syncthreads();
    if (t < B_ * TOPK_) out[SEL_OFF + t] = (float)sel_s[t % TOPK_];
    if (t < POOL_)      out[DIV_OFF + t] = divs[t];
}

// ---------------- gather selected prompts -> bf16 bpn (normalized) + bpT (raw, transposed) ----
__global__ void k_bp(const float* __restrict__ prompt, const int* __restrict__ sel,
                     __hip_bfloat16* __restrict__ bpn, __hip_bfloat16* __restrict__ bpT) {
    int w = threadIdx.x >> 6, lane = threadIdx.x & 63;
    int l = blockIdx.x * 4 + w;          // 0..319
    int k = sel[l >> 6];
    const float* src = prompt + ((size_t)k * LEN_ + (l & 63)) * D_ + lane * 4;
    float4 v = *(const float4*)src;
    float s = v.x * v.x + v.y * v.y + v.z * v.z + v.w * v.w;
    for (int m2 = 1; m2 < 64; m2 <<= 1) s += __shfl_xor(s, m2, 64);
    float inv = 1.0f / fmaxf(sqrtf(s), 1e-12f);
    int d0 = lane * 4;
    bpn[l * D_ + d0 + 0] = __float2bfloat16(v.x * inv);
    bpn[l * D_ + d0 + 1] = __float2bfloat16(v.y * inv);
    bpn[l * D_ + d0 + 2] = __float2bfloat16(v.z * inv);
    bpn[l * D_ + d0 + 3] = __float2bfloat16(v.w * inv);
    bpT[(d0 + 0) * L_ + l] = __float2bfloat16(v.x);
    bpT[(d0 + 1) * L_ + l] = __float2bfloat16(v.y);
    bpT[(d0 + 2) * L_ + l] = __float2bfloat16(v.z);
    bpT[(d0 + 3) * L_ + l] = __float2bfloat16(v.w);
}

// ---------------- fused depth attention: softmax((q/||q||) Kn^T / 16) V ----------------
__global__ __launch_bounds__(256, 1)
void k_attn(const float* __restrict__ depth, const __hip_bfloat16* __restrict__ bpn,
            const __hip_bfloat16* __restrict__ bpT, float* __restrict__ out) {
    __shared__ __hip_bfloat16 qn[64 * 264];         // 33792 B, q tile bf16 (UNnormalized), stride 264
    __shared__ __hip_bfloat16 P_lds[4][16 * 328];   // 41984 B, per-wave P, stride 328
    __shared__ __hip_bfloat16 chunk[160 * 264];     // 84480 B, staging (bpn 160x264 / bpT 128x328)
    __shared__ float rnorm_s[64];                   // per-row 1/||q||

    const int tid = threadIdx.x;
    const int w = tid >> 6, lane = tid & 63;
    const int b = blockIdx.y;
    const int m0 = blockIdx.x * 64;

    // ---- q prep: wave-local (wave w owns rows w*16..w*16+15); no __syncthreads needed ----
    {
        const int r = w * 16 + (lane >> 2);         // row within 64-row tile
        const int q4 = lane & 3;                    // quarter of the row
        const float4* src = (const float4*)(depth + ((size_t)b * M_ + m0 + r) * D_ + q4 * 64);
        float4 v[16];
        #pragma unroll
        for (int i = 0; i < 16; ++i) v[i] = src[i];
        float s = 0.f;
        #pragma unroll
        for (int i = 0; i < 16; ++i) s += v[i].x * v[i].x + v[i].y * v[i].y + v[i].z * v[i].z + v[i].w * v[i].w;
        s += __shfl_xor(s, 1, 64);
        s += __shfl_xor(s, 2, 64);
        if (q4 == 0) rnorm_s[r] = 1.0f / fmaxf(sqrtf(s), 1e-12f);
        __hip_bfloat16* dst = &qn[r * 264 + q4 * 64];
        #pragma unroll
        for (int jb = 0; jb < 8; ++jb) {
            union { bf16x8 v8; __hip_bfloat16 h[8]; } u;
            float4 a = v[jb * 2], c2 = v[jb * 2 + 1];
            u.h[0] = __float2bfloat16(a.x);  u.h[1] = __float2bfloat16(a.y);
            u.h[2] = __float2bfloat16(a.z);  u.h[3] = __float2bfloat16(a.w);
            u.h[4] = __float2bfloat16(c2.x); u.h[5] = __float2bfloat16(c2.y);
            u.h[6] = __float2bfloat16(c2.z); u.h[7] = __float2bfloat16(c2.w);
            *(bf16x8*)(dst + jb * 8) = u.v8;
        }
    }

    // A fragments (wave-local rows; lgkmcnt inserted by compiler)
    bf16x8 afr[8];
    {
        const __hip_bfloat16* base = &qn[(w * 16 + (lane & 15)) * 264 + ((lane >> 4) * 8)];
        #pragma unroll
        for (int kt = 0; kt < 8; ++kt) afr[kt] = *(const bf16x8*)(base + kt * 32);
    }

    f32x4 accS[20];
    #pragma unroll
    for (int i = 0; i < 20; ++i) { f32x4 z = {0.f, 0.f, 0.f, 0.f}; accS[i] = z; }

    // S = q * bpn^T  (two 160-row K chunks staged in LDS)
    for (int c = 0; c < 2; ++c) {
        __syncthreads();
        const uint4* src = (const uint4*)(bpn + (size_t)c * 160 * D_);
        for (int it = 0; it < 20; ++it) {
            int v = it * 256 + tid;                 // 5120 uint4 = 160 rows * 32
            int l = v >> 5, ko = (v & 31) * 8;
            *(uint4*)&chunk[l * 264 + ko] = src[v];
        }
        __syncthreads();
        #pragma unroll
        for (int lt = 0; lt < 10; ++lt) {
            const __hip_bfloat16* bb = &chunk[(lt * 16 + (lane & 15)) * 264 + ((lane >> 4) * 8)];
            #pragma unroll
            for (int kt = 0; kt < 8; ++kt) {
                bf16x8 bfr = *(const bf16x8*)(bb + kt * 32);
                accS[c * 10 + lt] = __builtin_amdgcn_mfma_f32_16x16x32_bf16(afr[kt], bfr, accS[c * 10 + lt], 0, 0, 0);
            }
        }
    }

    // in-register softmax; logit = raw_dot * (rnorm/16); store unnormalized exp to P_lds (bf16)
    float inv[4];
    #pragma unroll
    for (int r = 0; r < 4; ++r) {
        const float sc = rnorm_s[w * 16 + (lane >> 4) * 4 + r] * 0.0625f;
        float mx = accS[0][r];
        #pragma unroll
        for (int ltt = 1; ltt < 20; ++ltt) mx = fmaxf(mx, accS[ltt][r]);
        mx = fmaxf(mx, __shfl_xor(mx, 1, 64));
        mx = fmaxf(mx, __shfl_xor(mx, 2, 64));
        mx = fmaxf(mx, __shfl_xor(mx, 4, 64));
        mx = fmaxf(mx, __shfl_xor(mx, 8, 64));
        const float mxl = mx * sc;
        float sum = 0.f;
        __hip_bfloat16* prow = &P_lds[w][((lane >> 4) * 4 + r) * 328];
        #pragma unroll
        for (int ltt = 0; ltt < 20; ++ltt) {
            float e = __expf(accS[ltt][r] * sc - mxl);
            sum += e;
            prow[ltt * 16 + (lane & 15)] = __float2bfloat16(e);
        }
        sum += __shfl_xor(sum, 1, 64);
        sum += __shfl_xor(sum, 2, 64);
        sum += __shfl_xor(sum, 4, 64);
        sum += __shfl_xor(sum, 8, 64);
        inv[r] = 1.0f / sum;
    }

    // A fragments for PV from own wave's P tile
    bf16x8 a2[10];
    {
        const __hip_bfloat16* base = &P_lds[w][(lane & 15) * 328 + ((lane >> 4) * 8)];
        #pragma unroll
        for (int kt = 0; kt < 10; ++kt) a2[kt] = *(const bf16x8*)(base + kt * 32);
    }

    f32x4 accO[16];
    #pragma unroll
    for (int i = 0; i < 16; ++i) { f32x4 z = {0.f, 0.f, 0.f, 0.f}; accO[i] = z; }

    // O = P * V  (V^T staged in two 128-d-row chunks)
    for (int nc = 0; nc < 2; ++nc) {
        __syncthreads();
        const uint4* src = (const uint4*)(bpT + (size_t)nc * 128 * L_);
        for (int it = 0; it < 20; ++it) {
            int v = it * 256 + tid;                 // 5120 uint4 = 128 rows * 40
            int n = v / 40, ko = (v % 40) * 8;
            *(uint4*)&chunk[n * 328 + ko] = src[v];
        }
        __syncthreads();
        #pragma unroll
        for (int nt = 0; nt < 8; ++nt) {
            const __hip_bfloat16* bb = &chunk[(nt * 16 + (lane & 15)) * 328 + ((lane >> 4) * 8)];
            f32x4 acc = accO[nc * 8 + nt];
            #pragma unroll
            for (int kt = 0; kt < 10; ++kt) {
                bf16x8 bfr = *(const bf16x8*)(bb + kt * 32);
                acc = __builtin_amdgcn_mfma_f32_16x16x32_bf16(a2[kt], bfr, acc, 0, 0, 0);
            }
            accO[nc * 8 + nt] = acc;
        }
    }

    // epilogue: scale by 1/rowsum, store f32 (lanes cover 4 full 64B sectors per instr)
    float* obase = out + ((size_t)b * M_ + m0 + w * 16) * D_;
    #pragma unroll
    for (int i = 0; i < 16; ++i) {
        int n = (i >> 3) * 128 + (i & 7) * 16 + (lane & 15);
        #pragma unroll
        for (int r = 0; r < 4; ++r) {
            int row = (lane >> 4) * 4 + r;
            obase[(size_t)row * D_ + n] = accO[i][r] * inv[r];
        }
    }
}

extern "C" void kernel_launch(void* const* d_in, const int* in_sizes, int n_in,
                              void* d_out, int out_size, void* d_ws, size_t ws_size,
                              hipStream_t stream) {
    (void)in_sizes; (void)n_in; (void)out_size; (void)ws_size;
    const float* x      = (const float*)d_in[0];
    const float* depth  = (const float*)d_in[1];
    const float* prompt = (const float*)d_in[2];
    const float* pk     = (const float*)d_in[3];
    const float* W1     = (const float*)d_in[4];
    const float* b1     = (const float*)d_in[5];
    const float* g      = (const float*)d_in[6];
    const float* be     = (const float*)d_in[7];
    const float* W2     = (const float*)d_in[8];
    const float* b2     = (const float*)d_in[9];
    const float* hist   = (const float*)d_in[10];
    float* out = (float*)d_out;
    char*  ws  = (char*)d_ws;

    float* part   = (float*)(ws + WS_PART);
    float* xm     = (float*)(ws + WS_XMEAN);
    float* xnorm  = (float*)(ws + WS_XNORM);
    float* logits = (float*)(ws + WS_LOGITS);
    int*   sel    = (int*)(ws + WS_SEL);
    __hip_bfloat16* bpn = (__hip_bfloat16*)(ws + WS_BPN);
    __hip_bfloat16* bpT = (__hip_bfloat16*)(ws + WS_BPT);

    k_partial<<<dim3(32, 32), 256, 0, stream>>>(x, part);
    k_xmean<<<32, 256, 0, stream>>>(part, xm, xnorm);
    k_mlp<<<dim3(30, 32), 256, 0, stream>>>(xm, pk, W1, b1, g, be, W2, b2, logits);
    k_score<<<1, 256, 0, stream>>>(xm, xnorm, pk, hist, logits, out, sel);
    k_bp<<<80, 256, 0, stream>>>(prompt, sel, bpn, bpT);
    k_attn<<<dim3(64, 32), 256, 0, stream>>>(depth, bpn, bpT, out);
}